// Round 7
// baseline (1761.578 us; speedup 1.0000x reference)
//
#include <hip/hip_runtime.h>
#include <math.h>

typedef unsigned short ushort_t;
typedef _Float16 f16x8 __attribute__((ext_vector_type(8)));
typedef float f32x4 __attribute__((ext_vector_type(4)));

// ---------------- problem constants ----------------
// x: [2,320,4,14,14]  ori/v: [2,3,8,224,224]
// xp: channels-last [b][t][hw][c], rows m=(b*4+t)*2809+hw, 768 c
// out: [2,4,32,768] + out_pos same (d_out fp32)
// fp16 scaled split: v = hi + lo/2048, hi=f16(v), lo=f16((v-hi)*2048)
// GEMM: D = Ah·Bh + (Ah·Bl + Al·Bh)/2048  (ll term ~2^-22, dropped)

constexpr size_t OFF_SCALE_A = 0;                       // 320
constexpr size_t OFF_BIAS_A  = 320;                     // 320
constexpr size_t OFF_PSTAT   = 640;                     // 16
constexpr size_t OFF_SCALE_T = 656;                     // 768
constexpr size_t OFF_BIAS_T  = 1424;                    // 768
constexpr size_t OFF_SCALE_C = 2192;                    // 768
constexpr size_t OFF_BIAS_C  = 2960;                    // 768
constexpr size_t OFF_QS      = 3728;                    // 64
constexpr size_t OFF_PB0     = 3792;                    // 768 (proj bias, tp==0)
constexpr size_t OFF_PB1     = 4560;                    // 768 (proj bias, tp>0)
constexpr size_t OFF_POSWT   = 5328;                    // 27*768
constexpr size_t OFF_DWWT    = 26064;                   // 9*768
constexpr size_t OFF_SEL     = 32976;                   // 2*32*2809
constexpr size_t OFF_G       = 212752;                  // 6*32*2841
constexpr size_t OFF_SCORE   = 758224;                  // 6*32*2809 (first 3072 = bn scratch)
constexpr size_t OFF_XP      = 1297552;                 // 22472*768
constexpr size_t OFF_W1H     = 18556048;                // 2944*2848 ushort = 4192256 f
constexpr size_t OFF_W1L     = 22748304;                // 4192256 f
// region A: vh/vl/pwh/pwl (alive tconv->proj) then kth/ktl (ktrans->fc1)
constexpr size_t OFF_A       = 26940560;                // 13123584 f
constexpr size_t A_VH  = 0;                             // 2408448 ushort = 1204224 f
constexpr size_t A_VL  = 1204224;
constexpr size_t A_PWH = 2408448;                       // 768*2304 ushort = 884736 f
constexpr size_t A_PWL = 3293184;
constexpr size_t A_KTH = 0;                             // 4608*2848 ushort = 6561792 f
constexpr size_t A_KTL = 6561792;
// score MFMA operands
constexpr size_t OFF_W2H = 40064144;                    // 2816*2848 ushort = 4009984 f
constexpr size_t OFF_W2L = 44074128;
constexpr size_t OFF_GH  = 48084112;                    // 256*2848 ushort = 364544 f
constexpr size_t OFF_GL  = 48448656;
constexpr size_t NEED_FLOATS = 48813200;                // 195.25 MB (proven budget >= 205.2 MB)

__device__ inline void split_f16(float v, ushort_t& hb, ushort_t& lb) {
  _Float16 h = (_Float16)v;
  _Float16 l = (_Float16)((v - (float)h) * 2048.0f);
  union { _Float16 f; ushort_t u; } cvh, cvl; cvh.f = h; cvl.f = l;
  hb = cvh.u; lb = cvl.u;
}
__device__ inline float us2f(ushort_t u) {
  union { _Float16 f; ushort_t u; } c; c.u = u; return (float)c.f;
}

// async global -> LDS, 16B per lane. LDS dest must be wave-uniform base + lane*16
// (our (srow=tid>>2, soct=tid&3) mapping gives exactly lane*16 within each wave).
__device__ __forceinline__ void gld16(const ushort_t* g, ushort_t* l) {
  __builtin_amdgcn_global_load_lds(
      (const __attribute__((address_space(1))) unsigned int*)(size_t)g,
      (__attribute__((address_space(3))) unsigned int*)(unsigned int)(size_t)l,
      16, 0, 0);
}

// ---------------- small reductions ----------------

__global__ void __launch_bounds__(256) bn_stats_x_kernel(
    const float* __restrict__ x, const float* __restrict__ gamma,
    const float* __restrict__ beta, float* __restrict__ scale, float* __restrict__ bias) {
  int c = blockIdx.x;  // 320
  __shared__ float rs[256], rs2[256];
  float s = 0.f, s2 = 0.f;
  for (int j = threadIdx.x; j < 1568; j += 256) {
    int b = j / 784, thw = j - b * 784;
    float t = x[(b * 320 + c) * 784 + thw];
    s += t; s2 += t * t;
  }
  rs[threadIdx.x] = s; rs2[threadIdx.x] = s2; __syncthreads();
  for (int off = 128; off > 0; off >>= 1) {
    if (threadIdx.x < off) { rs[threadIdx.x] += rs[threadIdx.x + off]; rs2[threadIdx.x] += rs2[threadIdx.x + off]; }
    __syncthreads();
  }
  if (threadIdx.x == 0) {
    float mean = rs[0] / 1568.f;
    float var  = rs2[0] / 1568.f - mean * mean;
    float sc = gamma[c] * rsqrtf(var + 1e-5f);
    scale[c] = sc; bias[c] = beta[c] - mean * sc;
  }
}

__global__ void __launch_bounds__(256) bnp_partial_kernel(
    const ushort_t* __restrict__ vh, const ushort_t* __restrict__ vl, float* __restrict__ stat) {
  int blk = blockIdx.x;            // 192 = 6 (b,o) * 32 chunks
  int bo = blk >> 5, chunk = blk & 31;
  int o = bo % 3;
  size_t base = (size_t)bo * 401408 + (size_t)chunk * 12544;
  float s = 0.f, s2 = 0.f;
  for (int i = threadIdx.x; i < 12544; i += 256) {
    float t = us2f(vh[base + i]) + us2f(vl[base + i]) * (1.f / 2048.f);
    s += t; s2 += t * t;
  }
  __shared__ float rs[256], rs2[256];
  rs[threadIdx.x] = s; rs2[threadIdx.x] = s2; __syncthreads();
  for (int off = 128; off > 0; off >>= 1) {
    if (threadIdx.x < off) { rs[threadIdx.x] += rs[threadIdx.x + off]; rs2[threadIdx.x] += rs2[threadIdx.x + off]; }
    __syncthreads();
  }
  if (threadIdx.x == 0) { atomicAdd(&stat[o], rs[0]); atomicAdd(&stat[3 + o], rs2[0]); }
}

__global__ void bnp_final_kernel(float* __restrict__ stat,
                                 const float* __restrict__ g, const float* __restrict__ b) {
  int o = threadIdx.x;
  if (o < 3) {
    float mean = stat[o] / 802816.f;
    float var  = stat[3 + o] / 802816.f - mean * mean;
    float sc = g[o] * rsqrtf(var + 1e-5f);
    stat[6 + o] = sc; stat[9 + o] = b[o] - mean * sc;
  }
}

__global__ void __launch_bounds__(256) bn_sums_cl_kernel(
    const float* __restrict__ xp, float* __restrict__ sums, int frame0, int nrows) {
  int c = threadIdx.x;
  float s0 = 0.f, s1 = 0.f, s2 = 0.f, q0 = 0.f, q1 = 0.f, q2 = 0.f;
  int start = blockIdx.x * 128;
  int end = start + 128; if (end > nrows) end = nrows;
  for (int i = start; i < end; ++i) {
    int grow;
    if (frame0) { int b = i / 2809; grow = b * 11236 + (i - b * 2809); }
    else grow = i;
    const float* row = xp + (size_t)grow * 768;
    float v0 = row[c], v1 = row[c + 256], v2 = row[c + 512];
    s0 += v0; q0 += v0 * v0; s1 += v1; q1 += v1 * v1; s2 += v2; q2 += v2 * v2;
  }
  atomicAdd(&sums[c], s0);        atomicAdd(&sums[768 + c], q0);
  atomicAdd(&sums[c + 256], s1);  atomicAdd(&sums[768 + c + 256], q1);
  atomicAdd(&sums[c + 512], s2);  atomicAdd(&sums[768 + c + 512], q2);
}

__global__ void __launch_bounds__(256) bn_finalize_kernel(
    const float* __restrict__ sums, const float* __restrict__ g, const float* __restrict__ b,
    float* __restrict__ scale, float* __restrict__ bias, float cnt) {
  int c = blockIdx.x * 256 + threadIdx.x;
  float mean = sums[c] / cnt;
  float var  = sums[768 + c] / cnt - mean * mean;
  float sc = g[c] * rsqrtf(var + 1e-5f);
  scale[c] = sc; bias[c] = b[c] - mean * sc;
}

__global__ void wtrans_kernel(const float* __restrict__ pw, const float* __restrict__ dw,
                              float* __restrict__ pwt, float* __restrict__ dwt) {
  int idx = blockIdx.x * 256 + threadIdx.x;
  if (idx < 20736) { int c = idx / 27, tap = idx - c * 27; pwt[tap * 768 + c] = pw[idx]; }
  if (idx < 6912)  { int c = idx / 9,  tap = idx - c * 9;  dwt[tap * 768 + c] = dw[idx]; }
}

// fold BN_p scale into proj weights (f16 split) + two bias variants (tp==0 lacks kt=0 taps)
__global__ void __launch_bounds__(256) pwfold_kernel(
    const float* __restrict__ w, const float* __restrict__ pb, const float* __restrict__ pstat,
    ushort_t* __restrict__ pwh, ushort_t* __restrict__ pwl,
    float* __restrict__ pb0, float* __restrict__ pb1) {
  int n = blockIdx.x;  // 768
  float sp[3] = {pstat[6], pstat[7], pstat[8]};
  float bp[3] = {pstat[9], pstat[10], pstat[11]};
  float bsA = 0.f, bs0 = 0.f;
  for (int k = threadIdx.x; k < 2304; k += 256) {
    float wv = w[(size_t)n * 2304 + k];
    int ic = k / 768, rem = k - ic * 768;
    ushort_t h, l;
    split_f16(wv * sp[ic], h, l);
    pwh[(size_t)n * 2304 + k] = h; pwl[(size_t)n * 2304 + k] = l;
    float t = bp[ic] * wv;
    bsA += t;
    if ((rem >> 8) == 0) bs0 += t;   // kt==0 taps
  }
  __shared__ float rA[256], r0[256];
  rA[threadIdx.x] = bsA; r0[threadIdx.x] = bs0; __syncthreads();
  for (int off = 128; off > 0; off >>= 1) {
    if (threadIdx.x < off) { rA[threadIdx.x] += rA[threadIdx.x + off]; r0[threadIdx.x] += r0[threadIdx.x + off]; }
    __syncthreads();
  }
  if (threadIdx.x == 0) {
    pb1[n] = pb[n] + rA[0];
    pb0[n] = pb[n] + rA[0] - r0[0];
  }
}

// fc1_w -> f16 split, padded [2944][2848]
__global__ void __launch_bounds__(256) w1conv_kernel(
    const float* __restrict__ w, ushort_t* __restrict__ wh, ushort_t* __restrict__ wl) {
  int n = blockIdx.x;  // 2944
  for (int k = threadIdx.x; k < 2848; k += 256) {
    float val = (n < 2841 && k < 2841) ? w[(size_t)n * 2841 + k] : 0.f;
    ushort_t h, l;
    split_f16(val, h, l);
    wh[(size_t)n * 2848 + k] = h; wl[(size_t)n * 2848 + k] = l;
  }
}

// fc2_w -> f16 split, padded [2816][2848]
__global__ void __launch_bounds__(256) w2conv_kernel(
    const float* __restrict__ w, ushort_t* __restrict__ wh, ushort_t* __restrict__ wl) {
  int n = blockIdx.x;  // 2816
  for (int k = threadIdx.x; k < 2848; k += 256) {
    float val = (n < 2809 && k < 2841) ? w[(size_t)n * 2841 + k] : 0.f;
    ushort_t h, l;
    split_f16(val, h, l);
    wh[(size_t)n * 2848 + k] = h; wl[(size_t)n * 2848 + k] = l;
  }
}

// g -> f16 split, padded [256][2848]
__global__ void __launch_bounds__(256) gconv_kernel(
    const float* __restrict__ g, ushort_t* __restrict__ gh, ushort_t* __restrict__ gl) {
  int m = blockIdx.x;  // 256
  for (int k = threadIdx.x; k < 2848; k += 256) {
    float val = (m < 192 && k < 2841) ? g[(size_t)m * 2841 + k] : 0.f;
    ushort_t h, l;
    split_f16(val, h, l);
    gh[(size_t)m * 2848 + k] = h; gl[(size_t)m * 2848 + k] = l;
  }
}

// K-matrix transpose+convert: Kt[m=(b,t,c)][k] f16 split, k-contiguous
__global__ void __launch_bounds__(256) ktrans_kernel(
    const float* __restrict__ xp, const float* __restrict__ out,
    const float* __restrict__ sc, const float* __restrict__ bc,
    ushort_t* __restrict__ kth, ushort_t* __restrict__ ktl) {
  __shared__ float T[64][65];
  int m0 = blockIdx.x * 64;      // 72 tiles
  int k0 = blockIdx.y * 64;      // 45 tiles
  int b = m0 / 2304, t_l = (m0 % 2304) / 768, c0 = m0 % 768;
  int tid = threadIdx.x;
  int cr = tid & 63, kq = tid >> 6;
  int c = c0 + cr;
  float scc = sc[c], bcc = bc[c];
#pragma unroll
  for (int p = 0; p < 16; ++p) {
    int k_rel = p * 4 + kq;
    int k = k0 + k_rel;
    float val = 0.f;
    if (k < 32) val = out[(size_t)(b * 128 + k) * 768 + c];
    else if (k < 2841) val = xp[((size_t)(b * 4 + t_l + 1) * 2809 + (k - 32)) * 768 + c] * scc + bcc;
    T[k_rel][cr] = val;
  }
  __syncthreads();
#pragma unroll
  for (int p = 0; p < 16; ++p) {
    int row_c = p * 4 + kq;
    int m = m0 + row_c;
    int k = k0 + cr;
    if (k < 2848) {
      ushort_t h, l;
      split_f16(T[cr][row_c], h, l);
      kth[(size_t)m * 2848 + k] = h;
      ktl[(size_t)m * 2848 + k] = l;
    }
  }
}

// ---------------- tconv GEMM: writes raw v as f16 split ----------------
__global__ void __launch_bounds__(256) tconv_gemm_kernel(
    const float* __restrict__ x, const float* __restrict__ w,
    const float* __restrict__ tb, const float* __restrict__ ori,
    const float* __restrict__ sa, const float* __restrict__ ba,
    ushort_t* __restrict__ vh, ushort_t* __restrict__ vl) {
  __shared__ float As[16][68];
  __shared__ float Bs[16][68];
  int m0 = blockIdx.x * 64, n0 = blockIdx.y * 64;
  int tid = threadIdx.x, tx = tid & 15, ty = tid >> 4;
  int mm = tid & 63, ldk = tid >> 6;
  int m_l = m0 + mm;
  bool mval = m_l < 1568;
  int mc = mval ? m_l : 0;
  int b_l = mc / 784, thw_l = mc - b_l * 784;
  float acc[4][4] = {{0.f}};
  for (int k0 = 0; k0 < 320; k0 += 16) {
#pragma unroll
    for (int i = 0; i < 4; ++i) {
      int kk = ldk + i * 4;
      int kg = k0 + kk;
      As[kk][mm] = mval ? x[(b_l * 320 + kg) * 784 + thw_l] * sa[kg] + ba[kg] : 0.f;
      Bs[kk][mm] = w[kg * 1536 + n0 + mm];
    }
    __syncthreads();
#pragma unroll
    for (int kk = 0; kk < 16; ++kk) {
      float4 a4 = *(const float4*)&As[kk][ty * 4];
      float4 b4 = *(const float4*)&Bs[kk][tx * 4];
      float av[4] = {a4.x, a4.y, a4.z, a4.w};
      float bv[4] = {b4.x, b4.y, b4.z, b4.w};
#pragma unroll
      for (int r = 0; r < 4; ++r)
#pragma unroll
        for (int s = 0; s < 4; ++s) acc[r][s] += av[r] * bv[s];
    }
    __syncthreads();
  }
#pragma unroll
  for (int r = 0; r < 4; ++r) {
    int m = m0 + ty * 4 + r;
    if (m >= 1568) continue;
    int b = m / 784, thw = m - b * 784;
    int t = thw / 196, h = (thw / 14) % 14, wd = thw % 14;
#pragma unroll
    for (int s = 0; s < 4; ++s) {
      int n = n0 + tx * 4 + s;
      int o = n >> 9, k = (n >> 8) & 1, p = (n >> 4) & 15, q = n & 15;
      float val = acc[r][s] + tb[o];
      val = fminf(fmaxf(val, 0.f), 6.f);
      size_t idx = ((size_t)((b * 3 + o) * 8 + t * 2 + k) * 224 + (h * 16 + p)) * 224 + (wd * 16 + q);
      ushort_t hb, lb;
      split_f16(val + ori[idx], hb, lb);
      vh[idx] = hb; vl[idx] = lb;
    }
  }
}

// ================= split-f16 MFMA GEMMs =================
// Block tile 128(M) x 64(N), 4 waves each 64x32 -> 8 D-tiles x2 acc = 64 AGPRs.
// A staged in LDS (rows x32 k, 64B stride); B-FRAGMENTS READ DIRECTLY FROM GLOBAL
// (16 rows x 64B coalesced segments, L1/L2-hot) -> LDS traffic 12->8 b128/wave/kstep.
// MFMA 16x16x32_f16: A[m=lane&15][k=quad*8+j]; B[k=quad*8+j][n=lane&15];
// D[row=quad*4+r][col=lane&15].

// proj: xp[m][n] = (Ah.Bh + (Ah.Bl+Al.Bh)/2048) + bias(tp,n);  M=22472, N=768, K=2304
__global__ void __launch_bounds__(256) mfma_proj_kernel(
    const ushort_t* __restrict__ vh, const ushort_t* __restrict__ vl,
    const ushort_t* __restrict__ pwh, const ushort_t* __restrict__ pwl,
    const float* __restrict__ pb0, const float* __restrict__ pb1, float* __restrict__ xp) {
  __shared__ __align__(16) ushort_t Ah[128 * 32];
  __shared__ __align__(16) ushort_t Al[128 * 32];
  int m0 = blockIdx.x * 128, n0 = blockIdx.y * 64;
  int tid = threadIdx.x;
  int lane = tid & 63, wave = tid >> 6;
  int wm = wave & 1, wn = wave >> 1;   // wn in 0..1
  int srow = tid >> 2, soct = tid & 3;
  int fr = lane & 15, quad = lane >> 4;
  int rb[2], rtp[2], ry[2], rx[2]; bool rv[2];
#pragma unroll
  for (int i = 0; i < 2; ++i) {
    int m = m0 + srow + 64 * i;
    rv[i] = m < 22472;
    int mc = rv[i] ? m : 0;
    int b = mc / 11236, r = mc - b * 11236;
    int tp = r / 2809, hw = r - tp * 2809;
    rb[i] = b; rtp[i] = tp; ry[i] = hw / 53; rx[i] = hw - (hw / 53) * 53;
  }
  // B-fragment global base: row n0+wn*32+fr, k-octet quad
  const ushort_t* fBh = pwh + (size_t)(n0 + wn * 32 + fr) * 2304 + quad * 8;
  const ushort_t* fBl = pwl + (size_t)(n0 + wn * 32 + fr) * 2304 + quad * 8;
  f32x4 accH[4][2] = {};
  f32x4 accC[4][2] = {};
  for (int k0 = 0; k0 < 2304; k0 += 32) {
    // A: gathered (8B-aligned only) -> VGPR roundtrip
    int k = k0 + soct * 8;
    int ic = k / 768, rem = k - ic * 768;
    int kt = rem >> 8, ky = (rem >> 4) & 15, kx = rem & 15;
#pragma unroll
    for (int i = 0; i < 2; ++i) {
      int row = srow + 64 * i;
      int ls = row * 32 + soct * 8;
      int t_in = rtp[i] * 2 - 1 + kt;
      if (rv[i] && t_in >= 0 && t_in < 8) {
        size_t g = ((size_t)((rb[i] * 3 + ic) * 8 + t_in) * 224 + (ry[i] * 4 + ky)) * 224 + rx[i] * 4 + kx;
        *(uint2*)&Ah[ls]     = *(const uint2*)&vh[g];
        *(uint2*)&Ah[ls + 4] = *(const uint2*)&vh[g + 4];
        *(uint2*)&Al[ls]     = *(const uint2*)&vl[g];
        *(uint2*)&Al[ls + 4] = *(const uint2*)&vl[g + 4];
      } else {
        *(uint4*)&Ah[ls] = make_uint4(0, 0, 0, 0);
        *(uint4*)&Al[ls] = make_uint4(0, 0, 0, 0);
      }
    }
    // B fragments straight from global (L1/L2-hot)
    f16x8 bhf[2], blf[2];
#pragma unroll
    for (int nt = 0; nt < 2; ++nt) {
      bhf[nt] = *(const f16x8*)(fBh + (size_t)nt * 16 * 2304 + k0);
      blf[nt] = *(const f16x8*)(fBl + (size_t)nt * 16 * 2304 + k0);
    }
    __syncthreads();
#pragma unroll
    for (int mt = 0; mt < 4; ++mt) {
      int off = (wm * 64 + mt * 16 + fr) * 32 + quad * 8;
      f16x8 ah = *(const f16x8*)&Ah[off];
      f16x8 al = *(const f16x8*)&Al[off];
#pragma unroll
      for (int nt = 0; nt < 2; ++nt) {
        accH[mt][nt] = __builtin_amdgcn_mfma_f32_16x16x32_f16(ah, bhf[nt], accH[mt][nt], 0, 0, 0);
        accC[mt][nt] = __builtin_amdgcn_mfma_f32_16x16x32_f16(ah, blf[nt], accC[mt][nt], 0, 0, 0);
        accC[mt][nt] = __builtin_amdgcn_mfma_f32_16x16x32_f16(al, bhf[nt], accC[mt][nt], 0, 0, 0);
      }
    }
    __syncthreads();
  }
#pragma unroll
  for (int mt = 0; mt < 4; ++mt) {
#pragma unroll
    for (int nt = 0; nt < 2; ++nt) {
      int n = n0 + wn * 32 + nt * 16 + fr;
      float b0 = pb0[n], b1 = pb1[n];
#pragma unroll
      for (int r = 0; r < 4; ++r) {
        int m = m0 + wm * 64 + mt * 16 + quad * 4 + r;
        if (m < 22472) {
          int tp = (m % 11236) / 2809;
          xp[(size_t)m * 768 + n] = accH[mt][nt][r] + accC[mt][nt][r] * (1.f / 2048.f)
                                  + (tp == 0 ? b0 : b1);
        }
      }
    }
  }
}

// fc1 fused: h-tile -> gelu -> g[bt][tok][j] += tem^T.h (atomic); h never stored.
// M=4608 (b,t,c), N=2944 (j), K=2848.  A via gld16 LDS; B-frags from global.
__global__ void __launch_bounds__(256) mfma_fc1_kernel(
    const ushort_t* __restrict__ kth, const ushort_t* __restrict__ ktl,
    const ushort_t* __restrict__ w1h, const ushort_t* __restrict__ w1l,
    const float* __restrict__ fb, const float* __restrict__ outbuf, float* __restrict__ g) {
  __shared__ __align__(16) char smem[24960];
  ushort_t* Ah = (ushort_t*)smem;              // 8KB
  ushort_t* Al = (ushort_t*)(smem + 8192);     // 8KB
  float* hs   = (float*)smem;                  // 64*65 f = 16640B (reuse after K-loop)
  float* temS = (float*)(smem + 16640);        // 32*65 f = 8320B
  int m0 = blockIdx.x * 128, n0 = blockIdx.y * 64;
  int tid = threadIdx.x;
  int lane = tid & 63, wave = tid >> 6;
  int wm = wave & 1, wn = wave >> 1;           // wn in 0..1
  int srow = tid >> 2, soct = tid & 3;
  int fr = lane & 15, quad = lane >> 4;
  const size_t ROW64 = (size_t)64 * 2848;
  const ushort_t* gAh = kth + (size_t)(m0 + srow) * 2848 + soct * 8;
  const ushort_t* gAl = ktl + (size_t)(m0 + srow) * 2848 + soct * 8;
  ushort_t* lA  = &Ah[srow * 32 + soct * 8];
  ushort_t* lAl = &Al[srow * 32 + soct * 8];
  const ushort_t* fBh = w1h + (size_t)(n0 + wn * 32 + fr) * 2848 + quad * 8;
  const ushort_t* fBl = w1l + (size_t)(n0 + wn * 32 + fr) * 2848 + quad * 8;
  f32x4 accH[4][2] = {};
  f32x4 accC[4][2] = {};
  for (int k0 = 0; k0 < 2848; k0 += 32) {
    gld16(gAh + k0, lA);
    gld16(gAh + ROW64 + k0, lA + 64 * 32);
    gld16(gAl + k0, lAl);
    gld16(gAl + ROW64 + k0, lAl + 64 * 32);
    f16x8 bhf[2], blf[2];
#pragma unroll
    for (int nt = 0; nt < 2; ++nt) {
      bhf[nt] = *(const f16x8*)(fBh + (size_t)nt * 16 * 2848 + k0);
      blf[nt] = *(const f16x8*)(fBl + (size_t)nt * 16 * 2848 + k0);
    }
    __syncthreads();
#pragma unroll
    for (int mt = 0; mt < 4; ++mt) {
      int off = (wm * 64 + mt * 16 + fr) * 32 + quad * 8;
      f16x8 ah = *(const f16x8*)&Ah[off];
      f16x8 al = *(const f16x8*)&Al[off];
#pragma unroll
      for (int nt = 0; nt < 2; ++nt) {
        accH[mt][nt] = __builtin_amdgcn_mfma_f32_16x16x32_f16(ah, bhf[nt], accH[mt][nt], 0, 0, 0);
        accC[mt][nt] = __builtin_amdgcn_mfma_f32_16x16x32_f16(ah, blf[nt], accC[mt][nt], 0, 0, 0);
        accC[mt][nt] = __builtin_amdgcn_mfma_f32_16x16x32_f16(al, bhf[nt], accC[mt][nt], 0, 0, 0);
      }
    }
    __syncthreads();
  }
  // ---- fused epilogue: g[bt][tok][j] += sum_c tem[b][tok][c] * gelu(h[c][j]) ----
  int bt_lin = m0 / 768;
  int b = bt_lin / 3;
  int c0 = m0 % 768;
  int j_l = tid & 63, nh = tid >> 6;   // nh = wave -> tokens nh*8..+8 (temS read is broadcast)
  float gacc[8];
#pragma unroll
  for (int i = 0; i < 8; ++i) gacc[i] = 0.f;
  for (int half = 0; half < 2; ++half) {
    __syncthreads();
    for (int it = tid; it < 2048; it += 256) {
      int tok = it >> 6, cc = it & 63;
      temS[tok * 65 + cc] = outbuf[(size_t)(b * 128 + tok) * 768 + c0 + half * 64 + cc];
    }
    if (wm == half) {
#pragma unroll
      for (int mt = 0; mt < 4; ++mt) {
#pragma unroll
        for (int nt = 0; nt < 2; ++nt) {
          int col = wn * 32 + nt * 16 + fr;
          int n = n0 + col;
          float fbn = (n < 2841) ? fb[n] : 0.f;
#pragma unroll
          for (int r = 0; r < 4; ++r) {
            int row = mt * 16 + quad * 4 + r;
            float hv = 0.f;
            if (n < 2841) {
              float vv = accH[mt][nt][r] + accC[mt][nt][r] * (1.f / 2048.f) + fbn;
              hv = 0.5f * vv * (1.f + erff(vv * 0.70710678118654752f));
            }
            hs[row * 65 + col] = hv;
          }
        }
      }
    }
    __syncthreads();
    for (int cc = 0; cc < 64; ++cc) {
      float hv = hs[cc * 65 + j_l];
#pragma unroll
      for (int i = 0; i < 8; ++i)
        gacc[i] += temS[(nh * 8 + i) * 65 + cc] * hv;
    }
  }
  int j = n0 + j_l;
  if (j < 2841) {
#pragma unroll
    for (int i = 0; i < 8; ++i)
      atomicAdd(&g[((size_t)bt_lin * 32 + nh * 8 + i) * 2841 + j], gacc[i]);
  }
}

// score MFMA: score[m][hh] = (Gh.W2h + (Gh.W2l+Gl.W2h)/2048) + qs*f2b;  M=192(pad256), N=2809(pad2816), K=2848
__global__ void __launch_bounds__(256) mfma_score_kernel(
    const ushort_t* __restrict__ gh, const ushort_t* __restrict__ gl,
    const ushort_t* __restrict__ w2h, const ushort_t* __restrict__ w2l,
    const float* __restrict__ f2b, const float* __restrict__ qs, float* __restrict__ score) {
  __shared__ __align__(16) ushort_t Ah[128 * 32];
  __shared__ __align__(16) ushort_t Al[128 * 32];
  int m0 = blockIdx.x * 128, n0 = blockIdx.y * 64;
  int tid = threadIdx.x;
  int lane = tid & 63, wave = tid >> 6;
  int wm = wave & 1, wn = wave >> 1;
  int srow = tid >> 2, soct = tid & 3;
  int fr = lane & 15, quad = lane >> 4;
  const size_t ROW64 = (size_t)64 * 2848;
  const ushort_t* gAh = gh + (size_t)(m0 + srow) * 2848 + soct * 8;
  const ushort_t* gAl = gl + (size_t)(m0 + srow) * 2848 + soct * 8;
  ushort_t* lA  = &Ah[srow * 32 + soct * 8];
  ushort_t* lAl = &Al[srow * 32 + soct * 8];
  const ushort_t* fBh = w2h + (size_t)(n0 + wn * 32 + fr) * 2848 + quad * 8;
  const ushort_t* fBl = w2l + (size_t)(n0 + wn * 32 + fr) * 2848 + quad * 8;
  f32x4 accH[4][2] = {};
  f32x4 accC[4][2] = {};
  for (int k0 = 0; k0 < 2848; k0 += 32) {
    gld16(gAh + k0, lA);
    gld16(gAh + ROW64 + k0, lA + 64 * 32);
    gld16(gAl + k0, lAl);
    gld16(gAl + ROW64 + k0, lAl + 64 * 32);
    f16x8 bhf[2], blf[2];
#pragma unroll
    for (int nt = 0; nt < 2; ++nt) {
      bhf[nt] = *(const f16x8*)(fBh + (size_t)nt * 16 * 2848 + k0);
      blf[nt] = *(const f16x8*)(fBl + (size_t)nt * 16 * 2848 + k0);
    }
    __syncthreads();
#pragma unroll
    for (int mt = 0; mt < 4; ++mt) {
      int off = (wm * 64 + mt * 16 + fr) * 32 + quad * 8;
      f16x8 ah = *(const f16x8*)&Ah[off];
      f16x8 al = *(const f16x8*)&Al[off];
#pragma unroll
      for (int nt = 0; nt < 2; ++nt) {
        accH[mt][nt] = __builtin_amdgcn_mfma_f32_16x16x32_f16(ah, bhf[nt], accH[mt][nt], 0, 0, 0);
        accC[mt][nt] = __builtin_amdgcn_mfma_f32_16x16x32_f16(ah, blf[nt], accC[mt][nt], 0, 0, 0);
        accC[mt][nt] = __builtin_amdgcn_mfma_f32_16x16x32_f16(al, bhf[nt], accC[mt][nt], 0, 0, 0);
      }
    }
    __syncthreads();
  }
#pragma unroll
  for (int mt = 0; mt < 4; ++mt) {
#pragma unroll
    for (int nt = 0; nt < 2; ++nt) {
      int hh = n0 + wn * 32 + nt * 16 + fr;
      if (hh >= 2809) continue;
      float fb2 = f2b[hh];
#pragma unroll
      for (int r = 0; r < 4; ++r) {
        int m = m0 + wm * 64 + mt * 16 + quad * 4 + r;
        if (m < 192) {
          int bt = m >> 5, ntok = m & 31;
          int b = bt / 3;
          score[(size_t)m * 2809 + hh] = accH[mt][nt][r] + accC[mt][nt][r] * (1.f / 2048.f)
                                       + qs[b * 32 + ntok] * fb2;
        }
      }
    }
  }
}

// ---------------- fused tokenselector ----------------
__global__ void __launch_bounds__(256) sel_fused_kernel(
    const float* __restrict__ xp, const float* __restrict__ dwt, const float* __restrict__ db,
    const float* __restrict__ st, const float* __restrict__ bt,
    const float* __restrict__ pw, const float* __restrict__ pwb, float* __restrict__ sel) {
  __shared__ float row[768];
  __shared__ float part[32][9];
  int p = blockIdx.x;  // 5618
  int b = p / 2809, hw = p - b * 2809;
  int y = hw / 53, x = hw - y * 53;
  for (int c = threadIdx.x; c < 768; c += 256) {
    float acc = db[c];
    float scc = st[c], bcc = bt[c];
#pragma unroll
    for (int dy = 0; dy < 3; ++dy) {
      int yy = y + dy - 1; if (yy < 0 || yy >= 53) continue;
#pragma unroll
      for (int dx = 0; dx < 3; ++dx) {
        int xx = x + dx - 1; if (xx < 0 || xx >= 53) continue;
        float f0v = xp[((size_t)b * 11236 + yy * 53 + xx) * 768 + c] * scc + bcc;
        acc += f0v * dwt[(dy * 3 + dx) * 768 + c];
      }
    }
    row[c] = acc * fminf(fmaxf(acc + 3.f, 0.f), 6.f) * (1.f / 6.f);
  }
  __syncthreads();
  int n = threadIdx.x & 31, lane = threadIdx.x >> 5;
  float acc = 0.f;
  for (int c = lane; c < 768; c += 8) acc += row[c] * pw[n * 768 + c];
  part[n][lane] = acc;
  __syncthreads();
  if (threadIdx.x < 32) {
    float s = pwb[threadIdx.x];
#pragma unroll
    for (int l = 0; l < 8; ++l) s += part[threadIdx.x][l];
    sel[(size_t)(b * 32 + threadIdx.x) * 2809 + hw] = s;
  }
}

// ---------------- token argmax gather (pos computed on the fly) ----------------
__global__ void __launch_bounds__(256) tok_gather_kernel(
    const float* __restrict__ sel, const float* __restrict__ xp,
    const float* __restrict__ st, const float* __restrict__ bt,
    const float* __restrict__ poswt, const float* __restrict__ posb,
    float* __restrict__ out, float* __restrict__ qs) {
  int blk = blockIdx.x;  // 64
  int b = blk >> 5, n = blk & 31;
  const float* srow = sel + (size_t)blk * 2809;
  __shared__ float red[256];
  __shared__ int cnt;
  __shared__ int matches[64];
  float mx = -3.4e38f;
  for (int i = threadIdx.x; i < 2809; i += 256) mx = fmaxf(mx, srow[i]);
  red[threadIdx.x] = mx; __syncthreads();
  for (int off = 128; off > 0; off >>= 1) {
    if (threadIdx.x < off) red[threadIdx.x] = fmaxf(red[threadIdx.x], red[threadIdx.x + off]);
    __syncthreads();
  }
  float m = red[0];
  if (threadIdx.x == 0) cnt = 0;
  __syncthreads();
  for (int i = threadIdx.x; i < 2809; i += 256)
    if (srow[i] == m) { int id = atomicAdd(&cnt, 1); if (id < 64) matches[id] = i; }
  __syncthreads();
  int nm = cnt < 64 ? cnt : 64;
  float accf[3] = {0, 0, 0}, accp[3] = {0, 0, 0};
  float stc[3], btc[3];
#pragma unroll
  for (int i = 0; i < 3; ++i) { int c = threadIdx.x + i * 256; stc[i] = st[c]; btc[i] = bt[c]; }
  for (int j = 0; j < nm; ++j) {
    int hw = matches[j];
    int y = hw / 53, x = hw - y * 53;
#pragma unroll
    for (int i = 0; i < 3; ++i) {
      int c = threadIdx.x + i * 256;
      accf[i] += xp[((size_t)b * 11236 + hw) * 768 + c] * stc[i] + btc[i];
      float pv = posb[c];
      for (int dt = 0; dt < 3; ++dt) {
        int tt = dt - 1; if (tt < 0) continue;  // t=0 frame
        for (int dy = 0; dy < 3; ++dy) {
          int yy = y + dy - 1; if (yy < 0 || yy >= 53) continue;
          for (int dx = 0; dx < 3; ++dx) {
            int xx = x + dx - 1; if (xx < 0 || xx >= 53) continue;
            pv += xp[((size_t)(b * 4 + tt) * 2809 + yy * 53 + xx) * 768 + c]
                * poswt[((dt * 3 + dy) * 3 + dx) * 768 + c];
          }
        }
      }
      accp[i] += pv;
    }
  }
#pragma unroll
  for (int i = 0; i < 3; ++i) {
    int c = threadIdx.x + i * 256;
    out[(size_t)(b * 128 + n) * 768 + c] = accf[i];
    out[196608 + (size_t)(b * 128 + n) * 768 + c] = accp[i];
  }
  float s = accf[0] + accf[1] + accf[2];
  __syncthreads();
  red[threadIdx.x] = s; __syncthreads();
  for (int off = 128; off > 0; off >>= 1) {
    if (threadIdx.x < off) red[threadIdx.x] += red[threadIdx.x + off];
    __syncthreads();
  }
  if (threadIdx.x == 0) qs[blk] = red[0];
}

// ---------------- chain argmax gather (pos on the fly) ----------------
__global__ void __launch_bounds__(256) chain_gather_kernel(
    const float* __restrict__ score, const float* __restrict__ xp,
    const float* __restrict__ sc, const float* __restrict__ bc,
    const float* __restrict__ poswt, const float* __restrict__ posb,
    float* __restrict__ out) {
  int blk = blockIdx.x;  // 192
  int bt = blk >> 5, n = blk & 31;
  int b = bt / 3, t = bt - b * 3;
  const float* srow = score + (size_t)blk * 2809;
  __shared__ float red[256];
  __shared__ int cnt;
  __shared__ int matches[64];
  float mx = -3.4e38f;
  for (int i = threadIdx.x; i < 2809; i += 256) mx = fmaxf(mx, srow[i]);
  red[threadIdx.x] = mx; __syncthreads();
  for (int off = 128; off > 0; off >>= 1) {
    if (threadIdx.x < off) red[threadIdx.x] = fmaxf(red[threadIdx.x], red[threadIdx.x + off]);
    __syncthreads();
  }
  float m = red[0];
  if (threadIdx.x == 0) cnt = 0;
  __syncthreads();
  for (int i = threadIdx.x; i < 2809; i += 256)
    if (srow[i] == m) { int id = atomicAdd(&cnt, 1); if (id < 64) matches[id] = i; }
  __syncthreads();
  int nm = cnt < 64 ? cnt : 64;
  int frame = t + 1;
  float accf[3] = {0, 0, 0}, accp[3] = {0, 0, 0};
  float scc[3], bcc[3];
#pragma unroll
  for (int i = 0; i < 3; ++i) { int c = threadIdx.x + i * 256; scc[i] = sc[c]; bcc[i] = bc[c]; }
  for (int j = 0; j < nm; ++j) {
    int hw = matches[j];
    int y = hw / 53, x = hw - y * 53;
#pragma unroll
    for (int i = 0; i < 3; ++i) {
      int c = threadIdx.x + i * 256;
      size_t idx = ((size_t)(b * 4 + frame) * 2809 + hw) * 768 + c;
      accf[i] += xp[idx] * scc[i] + bcc[i];
      float pv = posb[c];
      for (int dt = 0; dt < 3; ++dt) {
        int tt = frame + dt - 1; if (tt < 0 || tt >= 4) continue;
        for (int dy = 0; dy < 3; ++dy) {
          int yy = y + dy - 1; if (yy < 0 || yy >= 53) continue;
          for (int dx = 0; dx < 3; ++dx) {
            int xx = x + dx - 1; if (xx < 0 || xx >= 53) continue;
            pv += xp[((size_t)(b * 4 + tt) * 2809 + yy * 53 + xx) * 768 + c]
                * poswt[((dt * 3 + dy) * 3 + dx) * 768 + c];
          }
        }
      }
      accp[i] += pv;
    }
  }
#pragma unroll
  for (int i = 0; i < 3; ++i) {
    int c = threadIdx.x + i * 256;
    out[(size_t)((b * 4 + frame) * 32 + n) * 768 + c] = accf[i];
    out[196608 + (size_t)((b * 4 + frame) * 32 + n) * 768 + c] = accp[i];
  }
}

// ---------------- launch ----------------
extern "C" void kernel_launch(void* const* d_in, const int* in_sizes, int n_in,
                              void* d_out, int out_size, void* d_ws, size_t ws_size,
                              hipStream_t stream) {
  const float* x       = (const float*)d_in[0];
  const float* ori     = (const float*)d_in[1];
  const float* bna_g   = (const float*)d_in[2];
  const float* bna_b   = (const float*)d_in[3];
  const float* tconv_w = (const float*)d_in[4];
  const float* tconv_b = (const float*)d_in[5];
  const float* bnp_g   = (const float*)d_in[6];
  const float* bnp_b   = (const float*)d_in[7];
  const float* proj_w  = (const float*)d_in[8];
  const float* proj_b  = (const float*)d_in[9];
  const float* pos_w   = (const float*)d_in[10];
  const float* pos_b   = (const float*)d_in[11];
  const float* bnt_g   = (const float*)d_in[12];
  const float* bnt_b   = (const float*)d_in[13];
  const float* dw_w    = (const float*)d_in[14];
  const float* dw_b    = (const float*)d_in[15];
  const float* pw_w    = (const float*)d_in[16];
  const float* pw_b    = (const float*)d_in[17];
  const float* bnc_g   = (const float*)d_in[18];
  const float* bnc_b   = (const float*)d_in[19];
  const float* fc1_w   = (const float*)d_in[20];
  const float* fc1_b   = (const float*)d_in[21];
  const float* fc2_w   = (const float*)d_in[22];
  const float* fc2_b   = (const float*)d_in[23];
  float* ws  = (float*)d_ws;
  float* out = (float*)d_out;

  if (ws_size < NEED_FLOATS * sizeof(float)) return;  // loud failure (output stays poisoned)

  float* scale_a = ws + OFF_SCALE_A;
  float* bias_a  = ws + OFF_BIAS_A;
  float* pstat   = ws + OFF_PSTAT;
  float* scale_t = ws + OFF_SCALE_T;
  float* bias_t  = ws + OFF_BIAS_T;
  float* scale_c = ws + OFF_SCALE_C;
  float* bias_c  = ws + OFF_BIAS_C;
  float* qsbuf   = ws + OFF_QS;
  float* pb0     = ws + OFF_PB0;
  float* pb1     = ws + OFF_PB1;
  float* poswt   = ws + OFF_POSWT;
  float* dwwt    = ws + OFF_DWWT;
  float* selbuf  = ws + OFF_SEL;
  float* gbuf    = ws + OFF_G;
  float* scorebuf= ws + OFF_SCORE;
  float* xpbuf   = ws + OFF_XP;
  float* sums_c  = scorebuf;          // scratch inside not-yet-written score
  float* sums_t  = scorebuf + 1536;

  ushort_t* vh  = (ushort_t*)(ws + OFF_A + A_VH);
  ushort_t* vl  = (ushort_t*)(ws + OFF_A + A_VL);
  ushort_t* pwh = (ushort_t*)(ws + OFF_A + A_PWH);
  ushort_t* pwl = (ushort_t*)(ws + OFF_A + A_PWL);
  ushort_t* kth = (ushort_t*)(ws + OFF_A + A_KTH);
  ushort_t* ktl = (ushort_t*)(ws + OFF_A + A_KTL);
  ushort_t* w1h = (ushort_t*)(ws + OFF_W1H);
  ushort_t* w1l = (ushort_t*)(ws + OFF_W1L);
  ushort_t* w2h = (ushort_t*)(ws + OFF_W2H);
  ushort_t* w2l = (ushort_t*)(ws + OFF_W2L);
  ushort_t* gh  = (ushort_t*)(ws + OFF_GH);
  ushort_t* gl  = (ushort_t*)(ws + OFF_GL);

  hipMemsetAsync(pstat, 0, 16 * sizeof(float), stream);
  hipMemsetAsync(sums_c, 0, 3072 * sizeof(float), stream);
  hipMemsetAsync(gbuf, 0, 545472 * sizeof(float), stream);

  bn_stats_x_kernel<<<320, 256, 0, stream>>>(x, bna_g, bna_b, scale_a, bias_a);
  tconv_gemm_kernel<<<dim3(25, 24), 256, 0, stream>>>(x, tconv_w, tconv_b, ori, scale_a, bias_a, vh, vl);
  bnp_partial_kernel<<<192, 256, 0, stream>>>(vh, vl, pstat);
  bnp_final_kernel<<<1, 64, 0, stream>>>(pstat, bnp_g, bnp_b);
  pwfold_kernel<<<768, 256, 0, stream>>>(proj_w, proj_b, pstat, pwh, pwl, pb0, pb1);
  mfma_proj_kernel<<<dim3(176, 12), 256, 0, stream>>>(vh, vl, pwh, pwl, pb0, pb1, xpbuf);
  bn_sums_cl_kernel<<<44, 256, 0, stream>>>(xpbuf, sums_t, 1, 5618);
  bn_sums_cl_kernel<<<176, 256, 0, stream>>>(xpbuf, sums_c, 0, 22472);
  bn_finalize_kernel<<<3, 256, 0, stream>>>(sums_t, bnt_g, bnt_b, scale_t, bias_t, 5618.f);
  bn_finalize_kernel<<<3, 256, 0, stream>>>(sums_c, bnc_g, bnc_b, scale_c, bias_c, 22472.f);
  wtrans_kernel<<<81, 256, 0, stream>>>(pos_w, dw_w, poswt, dwwt);
  sel_fused_kernel<<<5618, 256, 0, stream>>>(xpbuf, dwwt, dw_b, scale_t, bias_t, pw_w, pw_b, selbuf);
  tok_gather_kernel<<<64, 256, 0, stream>>>(selbuf, xpbuf, scale_t, bias_t, poswt, pos_b, out, qsbuf);
  ktrans_kernel<<<dim3(72, 45), 256, 0, stream>>>(xpbuf, out, scale_c, bias_c, kth, ktl);
  w1conv_kernel<<<2944, 256, 0, stream>>>(fc1_w, w1h, w1l);
  w2conv_kernel<<<2816, 256, 0, stream>>>(fc2_w, w2h, w2l);
  mfma_fc1_kernel<<<dim3(36, 46), 256, 0, stream>>>(kth, ktl, w1h, w1l, fc1_b, out, gbuf);
  gconv_kernel<<<256, 256, 0, stream>>>(gbuf, gh, gl);
  mfma_score_kernel<<<dim3(2, 44), 256, 0, stream>>>(gh, gl, w2h, w2l, fc2_b, qsbuf, scorebuf);
  chain_gather_kernel<<<192, 256, 0, stream>>>(scorebuf, xpbuf, scale_c, bias_c, poswt, pos_b, out);
}

// Round 8
// 1429.325 us; speedup vs baseline: 1.2325x; 1.2325x over previous
//
#include <hip/hip_runtime.h>
#include <math.h>

typedef unsigned short ushort_t;
typedef _Float16 f16x8 __attribute__((ext_vector_type(8)));
typedef float f32x4 __attribute__((ext_vector_type(4)));

// ---------------- problem constants ----------------
// x: [2,320,4,14,14]  ori/v: [2,3,8,224,224]
// xp: channels-last [b][t][hw][c], rows m=(b*4+t)*2809+hw, 768 c
// out: [2,4,32,768] + out_pos same (d_out fp32)
// fp16 scaled split: v = hi + lo/2048, hi=f16(v), lo=f16((v-hi)*2048)
// GEMM: D = Ah·Bh + (Ah·Bl + Al·Bh)/2048  (ll term ~2^-22, dropped)

constexpr size_t OFF_SCALE_A = 0;                       // 320
constexpr size_t OFF_BIAS_A  = 320;                     // 320
constexpr size_t OFF_PSTAT   = 640;                     // 16
constexpr size_t OFF_SCALE_T = 656;                     // 768
constexpr size_t OFF_BIAS_T  = 1424;                    // 768
constexpr size_t OFF_SCALE_C = 2192;                    // 768
constexpr size_t OFF_BIAS_C  = 2960;                    // 768
constexpr size_t OFF_QS      = 3728;                    // 64
constexpr size_t OFF_PB0     = 3792;                    // 768 (proj bias, tp==0)
constexpr size_t OFF_PB1     = 4560;                    // 768 (proj bias, tp>0)
constexpr size_t OFF_POSWT   = 5328;                    // 27*768
constexpr size_t OFF_DWWT    = 26064;                   // 9*768
constexpr size_t OFF_SEL     = 32976;                   // 2*32*2809
constexpr size_t OFF_G       = 212752;                  // 6*32*2841
constexpr size_t OFF_SCORE   = 758224;                  // 6*32*2809 (first 3072 = bn scratch)
constexpr size_t OFF_XP      = 1297552;                 // 22472*768
constexpr size_t OFF_W1H     = 18556048;                // 2944*2848 ushort = 4192256 f
constexpr size_t OFF_W1L     = 22748304;                // 4192256 f
// region A: vh/vl/pwh/pwl (alive tconv->proj) then kth/ktl (ktrans->fc1)
constexpr size_t OFF_A       = 26940560;                // 13123584 f
constexpr size_t A_VH  = 0;                             // 2408448 ushort = 1204224 f
constexpr size_t A_VL  = 1204224;
constexpr size_t A_PWH = 2408448;                       // 768*2304 ushort = 884736 f
constexpr size_t A_PWL = 3293184;
constexpr size_t A_KTH = 0;                             // 4608*2848 ushort = 6561792 f
constexpr size_t A_KTL = 6561792;
// score MFMA operands
constexpr size_t OFF_W2H = 40064144;                    // 2816*2848 ushort = 4009984 f
constexpr size_t OFF_W2L = 44074128;
constexpr size_t OFF_GH  = 48084112;                    // 256*2848 ushort = 364544 f
constexpr size_t OFF_GL  = 48448656;
constexpr size_t NEED_FLOATS = 48813200;                // 195.25 MB

__device__ inline void split_f16(float v, ushort_t& hb, ushort_t& lb) {
  _Float16 h = (_Float16)v;
  _Float16 l = (_Float16)((v - (float)h) * 2048.0f);
  union { _Float16 f; ushort_t u; } cvh, cvl; cvh.f = h; cvl.f = l;
  hb = cvh.u; lb = cvl.u;
}
__device__ inline float us2f(ushort_t u) {
  union { _Float16 f; ushort_t u; } c; c.u = u; return (float)c.f;
}

// async global -> LDS, 16B per lane. LDS dest must be wave-uniform base + lane*16
// (our (srow=tid>>2, soct=tid&3) mapping gives exactly lane*16 within each wave).
__device__ __forceinline__ void gld16(const ushort_t* g, ushort_t* l) {
  __builtin_amdgcn_global_load_lds(
      (const __attribute__((address_space(1))) unsigned int*)(size_t)g,
      (__attribute__((address_space(3))) unsigned int*)(unsigned int)(size_t)l,
      16, 0, 0);
}

// ---------------- small reductions ----------------

__global__ void __launch_bounds__(256) bn_stats_x_kernel(
    const float* __restrict__ x, const float* __restrict__ gamma,
    const float* __restrict__ beta, float* __restrict__ scale, float* __restrict__ bias) {
  int c = blockIdx.x;  // 320
  __shared__ float rs[256], rs2[256];
  float s = 0.f, s2 = 0.f;
  for (int j = threadIdx.x; j < 1568; j += 256) {
    int b = j / 784, thw = j - b * 784;
    float t = x[(b * 320 + c) * 784 + thw];
    s += t; s2 += t * t;
  }
  rs[threadIdx.x] = s; rs2[threadIdx.x] = s2; __syncthreads();
  for (int off = 128; off > 0; off >>= 1) {
    if (threadIdx.x < off) { rs[threadIdx.x] += rs[threadIdx.x + off]; rs2[threadIdx.x] += rs2[threadIdx.x + off]; }
    __syncthreads();
  }
  if (threadIdx.x == 0) {
    float mean = rs[0] / 1568.f;
    float var  = rs2[0] / 1568.f - mean * mean;
    float sc = gamma[c] * rsqrtf(var + 1e-5f);
    scale[c] = sc; bias[c] = beta[c] - mean * sc;
  }
}

__global__ void __launch_bounds__(256) bnp_partial_kernel(
    const ushort_t* __restrict__ vh, const ushort_t* __restrict__ vl, float* __restrict__ stat) {
  int blk = blockIdx.x;            // 192 = 6 (b,o) * 32 chunks
  int bo = blk >> 5, chunk = blk & 31;
  int o = bo % 3;
  size_t base = (size_t)bo * 401408 + (size_t)chunk * 12544;
  float s = 0.f, s2 = 0.f;
  for (int i = threadIdx.x; i < 12544; i += 256) {
    float t = us2f(vh[base + i]) + us2f(vl[base + i]) * (1.f / 2048.f);
    s += t; s2 += t * t;
  }
  __shared__ float rs[256], rs2[256];
  rs[threadIdx.x] = s; rs2[threadIdx.x] = s2; __syncthreads();
  for (int off = 128; off > 0; off >>= 1) {
    if (threadIdx.x < off) { rs[threadIdx.x] += rs[threadIdx.x + off]; rs2[threadIdx.x] += rs2[threadIdx.x + off]; }
    __syncthreads();
  }
  if (threadIdx.x == 0) { atomicAdd(&stat[o], rs[0]); atomicAdd(&stat[3 + o], rs2[0]); }
}

__global__ void bnp_final_kernel(float* __restrict__ stat,
                                 const float* __restrict__ g, const float* __restrict__ b) {
  int o = threadIdx.x;
  if (o < 3) {
    float mean = stat[o] / 802816.f;
    float var  = stat[3 + o] / 802816.f - mean * mean;
    float sc = g[o] * rsqrtf(var + 1e-5f);
    stat[6 + o] = sc; stat[9 + o] = b[o] - mean * sc;
  }
}

__global__ void __launch_bounds__(256) bn_sums_cl_kernel(
    const float* __restrict__ xp, float* __restrict__ sums, int frame0, int nrows) {
  int c = threadIdx.x;
  float s0 = 0.f, s1 = 0.f, s2 = 0.f, q0 = 0.f, q1 = 0.f, q2 = 0.f;
  int start = blockIdx.x * 128;
  int end = start + 128; if (end > nrows) end = nrows;
  for (int i = start; i < end; ++i) {
    int grow;
    if (frame0) { int b = i / 2809; grow = b * 11236 + (i - b * 2809); }
    else grow = i;
    const float* row = xp + (size_t)grow * 768;
    float v0 = row[c], v1 = row[c + 256], v2 = row[c + 512];
    s0 += v0; q0 += v0 * v0; s1 += v1; q1 += v1 * v1; s2 += v2; q2 += v2 * v2;
  }
  atomicAdd(&sums[c], s0);        atomicAdd(&sums[768 + c], q0);
  atomicAdd(&sums[c + 256], s1);  atomicAdd(&sums[768 + c + 256], q1);
  atomicAdd(&sums[c + 512], s2);  atomicAdd(&sums[768 + c + 512], q2);
}

__global__ void __launch_bounds__(256) bn_finalize_kernel(
    const float* __restrict__ sums, const float* __restrict__ g, const float* __restrict__ b,
    float* __restrict__ scale, float* __restrict__ bias, float cnt) {
  int c = blockIdx.x * 256 + threadIdx.x;
  float mean = sums[c] / cnt;
  float var  = sums[768 + c] / cnt - mean * mean;
  float sc = g[c] * rsqrtf(var + 1e-5f);
  scale[c] = sc; bias[c] = b[c] - mean * sc;
}

__global__ void wtrans_kernel(const float* __restrict__ pw, const float* __restrict__ dw,
                              float* __restrict__ pwt, float* __restrict__ dwt) {
  int idx = blockIdx.x * 256 + threadIdx.x;
  if (idx < 20736) { int c = idx / 27, tap = idx - c * 27; pwt[tap * 768 + c] = pw[idx]; }
  if (idx < 6912)  { int c = idx / 9,  tap = idx - c * 9;  dwt[tap * 768 + c] = dw[idx]; }
}

// fold BN_p scale into proj weights (f16 split) + two bias variants (tp==0 lacks kt=0 taps)
__global__ void __launch_bounds__(256) pwfold_kernel(
    const float* __restrict__ w, const float* __restrict__ pb, const float* __restrict__ pstat,
    ushort_t* __restrict__ pwh, ushort_t* __restrict__ pwl,
    float* __restrict__ pb0, float* __restrict__ pb1) {
  int n = blockIdx.x;  // 768
  float sp[3] = {pstat[6], pstat[7], pstat[8]};
  float bp[3] = {pstat[9], pstat[10], pstat[11]};
  float bsA = 0.f, bs0 = 0.f;
  for (int k = threadIdx.x; k < 2304; k += 256) {
    float wv = w[(size_t)n * 2304 + k];
    int ic = k / 768, rem = k - ic * 768;
    ushort_t h, l;
    split_f16(wv * sp[ic], h, l);
    pwh[(size_t)n * 2304 + k] = h; pwl[(size_t)n * 2304 + k] = l;
    float t = bp[ic] * wv;
    bsA += t;
    if ((rem >> 8) == 0) bs0 += t;   // kt==0 taps
  }
  __shared__ float rA[256], r0[256];
  rA[threadIdx.x] = bsA; r0[threadIdx.x] = bs0; __syncthreads();
  for (int off = 128; off > 0; off >>= 1) {
    if (threadIdx.x < off) { rA[threadIdx.x] += rA[threadIdx.x + off]; r0[threadIdx.x] += r0[threadIdx.x + off]; }
    __syncthreads();
  }
  if (threadIdx.x == 0) {
    pb1[n] = pb[n] + rA[0];
    pb0[n] = pb[n] + rA[0] - r0[0];
  }
}

// fc1_w -> f16 split, padded [2944][2848]
__global__ void __launch_bounds__(256) w1conv_kernel(
    const float* __restrict__ w, ushort_t* __restrict__ wh, ushort_t* __restrict__ wl) {
  int n = blockIdx.x;  // 2944
  for (int k = threadIdx.x; k < 2848; k += 256) {
    float val = (n < 2841 && k < 2841) ? w[(size_t)n * 2841 + k] : 0.f;
    ushort_t h, l;
    split_f16(val, h, l);
    wh[(size_t)n * 2848 + k] = h; wl[(size_t)n * 2848 + k] = l;
  }
}

// fc2_w -> f16 split, padded [2816][2848]
__global__ void __launch_bounds__(256) w2conv_kernel(
    const float* __restrict__ w, ushort_t* __restrict__ wh, ushort_t* __restrict__ wl) {
  int n = blockIdx.x;  // 2816
  for (int k = threadIdx.x; k < 2848; k += 256) {
    float val = (n < 2809 && k < 2841) ? w[(size_t)n * 2841 + k] : 0.f;
    ushort_t h, l;
    split_f16(val, h, l);
    wh[(size_t)n * 2848 + k] = h; wl[(size_t)n * 2848 + k] = l;
  }
}

// g -> f16 split, padded [256][2848]
__global__ void __launch_bounds__(256) gconv_kernel(
    const float* __restrict__ g, ushort_t* __restrict__ gh, ushort_t* __restrict__ gl) {
  int m = blockIdx.x;  // 256
  for (int k = threadIdx.x; k < 2848; k += 256) {
    float val = (m < 192 && k < 2841) ? g[(size_t)m * 2841 + k] : 0.f;
    ushort_t h, l;
    split_f16(val, h, l);
    gh[(size_t)m * 2848 + k] = h; gl[(size_t)m * 2848 + k] = l;
  }
}

// K-matrix transpose+convert: Kt[m=(b,t,c)][k] f16 split, k-contiguous
__global__ void __launch_bounds__(256) ktrans_kernel(
    const float* __restrict__ xp, const float* __restrict__ out,
    const float* __restrict__ sc, const float* __restrict__ bc,
    ushort_t* __restrict__ kth, ushort_t* __restrict__ ktl) {
  __shared__ float T[64][65];
  int m0 = blockIdx.x * 64;      // 72 tiles
  int k0 = blockIdx.y * 64;      // 45 tiles
  int b = m0 / 2304, t_l = (m0 % 2304) / 768, c0 = m0 % 768;
  int tid = threadIdx.x;
  int cr = tid & 63, kq = tid >> 6;
  int c = c0 + cr;
  float scc = sc[c], bcc = bc[c];
#pragma unroll
  for (int p = 0; p < 16; ++p) {
    int k_rel = p * 4 + kq;
    int k = k0 + k_rel;
    float val = 0.f;
    if (k < 32) val = out[(size_t)(b * 128 + k) * 768 + c];
    else if (k < 2841) val = xp[((size_t)(b * 4 + t_l + 1) * 2809 + (k - 32)) * 768 + c] * scc + bcc;
    T[k_rel][cr] = val;
  }
  __syncthreads();
#pragma unroll
  for (int p = 0; p < 16; ++p) {
    int row_c = p * 4 + kq;
    int m = m0 + row_c;
    int k = k0 + cr;
    if (k < 2848) {
      ushort_t h, l;
      split_f16(T[cr][row_c], h, l);
      kth[(size_t)m * 2848 + k] = h;
      ktl[(size_t)m * 2848 + k] = l;
    }
  }
}

// ---------------- tconv GEMM: writes raw v as f16 split ----------------
__global__ void __launch_bounds__(256) tconv_gemm_kernel(
    const float* __restrict__ x, const float* __restrict__ w,
    const float* __restrict__ tb, const float* __restrict__ ori,
    const float* __restrict__ sa, const float* __restrict__ ba,
    ushort_t* __restrict__ vh, ushort_t* __restrict__ vl) {
  __shared__ float As[16][68];
  __shared__ float Bs[16][68];
  int m0 = blockIdx.x * 64, n0 = blockIdx.y * 64;
  int tid = threadIdx.x, tx = tid & 15, ty = tid >> 4;
  int mm = tid & 63, ldk = tid >> 6;
  int m_l = m0 + mm;
  bool mval = m_l < 1568;
  int mc = mval ? m_l : 0;
  int b_l = mc / 784, thw_l = mc - b_l * 784;
  float acc[4][4] = {{0.f}};
  for (int k0 = 0; k0 < 320; k0 += 16) {
#pragma unroll
    for (int i = 0; i < 4; ++i) {
      int kk = ldk + i * 4;
      int kg = k0 + kk;
      As[kk][mm] = mval ? x[(b_l * 320 + kg) * 784 + thw_l] * sa[kg] + ba[kg] : 0.f;
      Bs[kk][mm] = w[kg * 1536 + n0 + mm];
    }
    __syncthreads();
#pragma unroll
    for (int kk = 0; kk < 16; ++kk) {
      float4 a4 = *(const float4*)&As[kk][ty * 4];
      float4 b4 = *(const float4*)&Bs[kk][tx * 4];
      float av[4] = {a4.x, a4.y, a4.z, a4.w};
      float bv[4] = {b4.x, b4.y, b4.z, b4.w};
#pragma unroll
      for (int r = 0; r < 4; ++r)
#pragma unroll
        for (int s = 0; s < 4; ++s) acc[r][s] += av[r] * bv[s];
    }
    __syncthreads();
  }
#pragma unroll
  for (int r = 0; r < 4; ++r) {
    int m = m0 + ty * 4 + r;
    if (m >= 1568) continue;
    int b = m / 784, thw = m - b * 784;
    int t = thw / 196, h = (thw / 14) % 14, wd = thw % 14;
#pragma unroll
    for (int s = 0; s < 4; ++s) {
      int n = n0 + tx * 4 + s;
      int o = n >> 9, k = (n >> 8) & 1, p = (n >> 4) & 15, q = n & 15;
      float val = acc[r][s] + tb[o];
      val = fminf(fmaxf(val, 0.f), 6.f);
      size_t idx = ((size_t)((b * 3 + o) * 8 + t * 2 + k) * 224 + (h * 16 + p)) * 224 + (wd * 16 + q);
      ushort_t hb, lb;
      split_f16(val + ori[idx], hb, lb);
      vh[idx] = hb; vl[idx] = lb;
    }
  }
}

// ================= split-f16 MFMA GEMMs =================
// Block tile 128(M) x 64(N), 4 waves each 64x32 -> 8 D-tiles x2 acc = 64 AGPRs.
// LDS tiles [rows][32 k] f16, row stride 64B. __launch_bounds__(256,3):
// cap unified regs at ~170 -> 3 blocks/CU (was 176 -> 2; occupancy was the binding pipe).
// MFMA 16x16x32_f16: A[m=lane&15][k=quad*8+j]; B[k=quad*8+j][n=lane&15];
// D[row=quad*4+r][col=lane&15].

// proj: xp[m][n] = (Ah.Bh + (Ah.Bl+Al.Bh)/2048) + bias(tp,n);  M=22472, N=768, K=2304
__global__ void __launch_bounds__(256, 3) mfma_proj_kernel(
    const ushort_t* __restrict__ vh, const ushort_t* __restrict__ vl,
    const ushort_t* __restrict__ pwh, const ushort_t* __restrict__ pwl,
    const float* __restrict__ pb0, const float* __restrict__ pb1, float* __restrict__ xp) {
  __shared__ __align__(16) ushort_t Ah[128 * 32];
  __shared__ __align__(16) ushort_t Al[128 * 32];
  __shared__ __align__(16) ushort_t Bh[64 * 32];
  __shared__ __align__(16) ushort_t Bl[64 * 32];
  int m0 = blockIdx.x * 128, n0 = blockIdx.y * 64;
  int tid = threadIdx.x;
  int lane = tid & 63, wave = tid >> 6;
  int wm = wave & 1, wn = wave >> 1;   // wn in 0..1
  int srow = tid >> 2, soct = tid & 3;
  int fr = lane & 15, quad = lane >> 4;
  int rb[2], rtp[2], ry[2], rx[2]; bool rv[2];
#pragma unroll
  for (int i = 0; i < 2; ++i) {
    int m = m0 + srow + 64 * i;
    rv[i] = m < 22472;
    int mc = rv[i] ? m : 0;
    int b = mc / 11236, r = mc - b * 11236;
    int tp = r / 2809, hw = r - tp * 2809;
    rb[i] = b; rtp[i] = tp; ry[i] = hw / 53; rx[i] = hw - (hw / 53) * 53;
  }
  const ushort_t* gBh = pwh + (size_t)(n0 + srow) * 2304 + soct * 8;
  const ushort_t* gBl = pwl + (size_t)(n0 + srow) * 2304 + soct * 8;
  ushort_t* lB = &Bh[srow * 32 + soct * 8];
  ushort_t* lBl = &Bl[srow * 32 + soct * 8];
  f32x4 accH[4][2] = {};
  f32x4 accC[4][2] = {};
  for (int k0 = 0; k0 < 2304; k0 += 32) {
    // B: async direct-to-LDS (16B aligned)
    gld16(gBh + k0, lB);
    gld16(gBl + k0, lBl);
    // A: gathered (8B-aligned only) -> VGPR roundtrip
    int k = k0 + soct * 8;
    int ic = k / 768, rem = k - ic * 768;
    int kt = rem >> 8, ky = (rem >> 4) & 15, kx = rem & 15;
#pragma unroll
    for (int i = 0; i < 2; ++i) {
      int row = srow + 64 * i;
      int ls = row * 32 + soct * 8;
      int t_in = rtp[i] * 2 - 1 + kt;
      if (rv[i] && t_in >= 0 && t_in < 8) {
        size_t g = ((size_t)((rb[i] * 3 + ic) * 8 + t_in) * 224 + (ry[i] * 4 + ky)) * 224 + rx[i] * 4 + kx;
        *(uint2*)&Ah[ls]     = *(const uint2*)&vh[g];
        *(uint2*)&Ah[ls + 4] = *(const uint2*)&vh[g + 4];
        *(uint2*)&Al[ls]     = *(const uint2*)&vl[g];
        *(uint2*)&Al[ls + 4] = *(const uint2*)&vl[g + 4];
      } else {
        *(uint4*)&Ah[ls] = make_uint4(0, 0, 0, 0);
        *(uint4*)&Al[ls] = make_uint4(0, 0, 0, 0);
      }
    }
    __syncthreads();
    f16x8 bhf[2], blf[2];
#pragma unroll
    for (int nt = 0; nt < 2; ++nt) {
      int off = (wn * 32 + nt * 16 + fr) * 32 + quad * 8;
      bhf[nt] = *(const f16x8*)&Bh[off];
      blf[nt] = *(const f16x8*)&Bl[off];
    }
#pragma unroll
    for (int mt = 0; mt < 4; ++mt) {
      int off = (wm * 64 + mt * 16 + fr) * 32 + quad * 8;
      f16x8 ah = *(const f16x8*)&Ah[off];
      f16x8 al = *(const f16x8*)&Al[off];
#pragma unroll
      for (int nt = 0; nt < 2; ++nt) {
        accH[mt][nt] = __builtin_amdgcn_mfma_f32_16x16x32_f16(ah, bhf[nt], accH[mt][nt], 0, 0, 0);
        accC[mt][nt] = __builtin_amdgcn_mfma_f32_16x16x32_f16(ah, blf[nt], accC[mt][nt], 0, 0, 0);
        accC[mt][nt] = __builtin_amdgcn_mfma_f32_16x16x32_f16(al, bhf[nt], accC[mt][nt], 0, 0, 0);
      }
    }
    __syncthreads();
  }
#pragma unroll
  for (int mt = 0; mt < 4; ++mt) {
#pragma unroll
    for (int nt = 0; nt < 2; ++nt) {
      int n = n0 + wn * 32 + nt * 16 + fr;
      float b0 = pb0[n], b1 = pb1[n];
#pragma unroll
      for (int r = 0; r < 4; ++r) {
        int m = m0 + wm * 64 + mt * 16 + quad * 4 + r;
        if (m < 22472) {
          int tp = (m % 11236) / 2809;
          xp[(size_t)m * 768 + n] = accH[mt][nt][r] + accC[mt][nt][r] * (1.f / 2048.f)
                                  + (tp == 0 ? b0 : b1);
        }
      }
    }
  }
}

// fc1 fused: h-tile -> gelu -> g[bt][tok][j] += tem^T.h (atomic); h never stored.
// M=4608 (b,t,c), N=2944 (j), K=2848.  All streams 16B-aligned -> full async staging.
__global__ void __launch_bounds__(256, 3) mfma_fc1_kernel(
    const ushort_t* __restrict__ kth, const ushort_t* __restrict__ ktl,
    const ushort_t* __restrict__ w1h, const ushort_t* __restrict__ w1l,
    const float* __restrict__ fb, const float* __restrict__ outbuf, float* __restrict__ g) {
  __shared__ __align__(16) char smem[24960];
  ushort_t* Ah = (ushort_t*)smem;              // 8KB
  ushort_t* Al = (ushort_t*)(smem + 8192);     // 8KB
  ushort_t* Bh = (ushort_t*)(smem + 16384);    // 4KB
  ushort_t* Bl = (ushort_t*)(smem + 20480);    // 4KB
  float* hs   = (float*)smem;                  // 64*65 f = 16640B (reuse after K-loop)
  float* temS = (float*)(smem + 16640);        // 32*65 f = 8320B
  int m0 = blockIdx.x * 128, n0 = blockIdx.y * 64;
  int tid = threadIdx.x;
  int lane = tid & 63, wave = tid >> 6;
  int wm = wave & 1, wn = wave >> 1;           // wn in 0..1
  int srow = tid >> 2, soct = tid & 3;
  int fr = lane & 15, quad = lane >> 4;
  const size_t ROW64 = (size_t)64 * 2848;
  const ushort_t* gAh = kth + (size_t)(m0 + srow) * 2848 + soct * 8;
  const ushort_t* gAl = ktl + (size_t)(m0 + srow) * 2848 + soct * 8;
  const ushort_t* gBh = w1h + (size_t)(n0 + srow) * 2848 + soct * 8;
  const ushort_t* gBl = w1l + (size_t)(n0 + srow) * 2848 + soct * 8;
  ushort_t* lA  = &Ah[srow * 32 + soct * 8];
  ushort_t* lAl = &Al[srow * 32 + soct * 8];
  ushort_t* lB  = &Bh[srow * 32 + soct * 8];
  ushort_t* lBl = &Bl[srow * 32 + soct * 8];
  f32x4 accH[4][2] = {};
  f32x4 accC[4][2] = {};
  for (int k0 = 0; k0 < 2848; k0 += 32) {
    gld16(gAh + k0, lA);
    gld16(gAh + ROW64 + k0, lA + 64 * 32);
    gld16(gAl + k0, lAl);
    gld16(gAl + ROW64 + k0, lAl + 64 * 32);
    gld16(gBh + k0, lB);
    gld16(gBl + k0, lBl);
    __syncthreads();
    f16x8 bhf[2], blf[2];
#pragma unroll
    for (int nt = 0; nt < 2; ++nt) {
      int off = (wn * 32 + nt * 16 + fr) * 32 + quad * 8;
      bhf[nt] = *(const f16x8*)&Bh[off];
      blf[nt] = *(const f16x8*)&Bl[off];
    }
#pragma unroll
    for (int mt = 0; mt < 4; ++mt) {
      int off = (wm * 64 + mt * 16 + fr) * 32 + quad * 8;
      f16x8 ah = *(const f16x8*)&Ah[off];
      f16x8 al = *(const f16x8*)&Al[off];
#pragma unroll
      for (int nt = 0; nt < 2; ++nt) {
        accH[mt][nt] = __builtin_amdgcn_mfma_f32_16x16x32_f16(ah, bhf[nt], accH[mt][nt], 0, 0, 0);
        accC[mt][nt] = __builtin_amdgcn_mfma_f32_16x16x32_f16(ah, blf[nt], accC[mt][nt], 0, 0, 0);
        accC[mt][nt] = __builtin_amdgcn_mfma_f32_16x16x32_f16(al, bhf[nt], accC[mt][nt], 0, 0, 0);
      }
    }
    __syncthreads();
  }
  // ---- fused epilogue: g[bt][tok][j] += sum_c tem[b][tok][c] * gelu(h[c][j]) ----
  int bt_lin = m0 / 768;
  int b = bt_lin / 3;
  int c0 = m0 % 768;
  int j_l = tid & 63, nh = tid >> 6;   // nh = wave -> tokens nh*8..+8 (temS read is broadcast)
  float gacc[8];
#pragma unroll
  for (int i = 0; i < 8; ++i) gacc[i] = 0.f;
  for (int half = 0; half < 2; ++half) {
    __syncthreads();
    for (int it = tid; it < 2048; it += 256) {
      int tok = it >> 6, cc = it & 63;
      temS[tok * 65 + cc] = outbuf[(size_t)(b * 128 + tok) * 768 + c0 + half * 64 + cc];
    }
    if (wm == half) {
#pragma unroll
      for (int mt = 0; mt < 4; ++mt) {
#pragma unroll
        for (int nt = 0; nt < 2; ++nt) {
          int col = wn * 32 + nt * 16 + fr;
          int n = n0 + col;
          float fbn = (n < 2841) ? fb[n] : 0.f;
#pragma unroll
          for (int r = 0; r < 4; ++r) {
            int row = mt * 16 + quad * 4 + r;
            float hv = 0.f;
            if (n < 2841) {
              float vv = accH[mt][nt][r] + accC[mt][nt][r] * (1.f / 2048.f) + fbn;
              hv = 0.5f * vv * (1.f + erff(vv * 0.70710678118654752f));
            }
            hs[row * 65 + col] = hv;
          }
        }
      }
    }
    __syncthreads();
    for (int cc = 0; cc < 64; ++cc) {
      float hv = hs[cc * 65 + j_l];
#pragma unroll
      for (int i = 0; i < 8; ++i)
        gacc[i] += temS[(nh * 8 + i) * 65 + cc] * hv;
    }
  }
  int j = n0 + j_l;
  if (j < 2841) {
#pragma unroll
    for (int i = 0; i < 8; ++i)
      atomicAdd(&g[((size_t)bt_lin * 32 + nh * 8 + i) * 2841 + j], gacc[i]);
  }
}

// score MFMA: score[m][hh] = (Gh.W2h + (Gh.W2l+Gl.W2h)/2048) + qs*f2b;  M=192(pad256), N=2809(pad2816), K=2848
__global__ void __launch_bounds__(256, 3) mfma_score_kernel(
    const ushort_t* __restrict__ gh, const ushort_t* __restrict__ gl,
    const ushort_t* __restrict__ w2h, const ushort_t* __restrict__ w2l,
    const float* __restrict__ f2b, const float* __restrict__ qs, float* __restrict__ score) {
  __shared__ __align__(16) ushort_t Ah[128 * 32];
  __shared__ __align__(16) ushort_t Al[128 * 32];
  __shared__ __align__(16) ushort_t Bh[64 * 32];
  __shared__ __align__(16) ushort_t Bl[64 * 32];
  int m0 = blockIdx.x * 128, n0 = blockIdx.y * 64;
  int tid = threadIdx.x;
  int lane = tid & 63, wave = tid >> 6;
  int wm = wave & 1, wn = wave >> 1;
  int srow = tid >> 2, soct = tid & 3;
  int fr = lane & 15, quad = lane >> 4;
  const size_t ROW64 = (size_t)64 * 2848;
  const ushort_t* gAh = gh + (size_t)(m0 + srow) * 2848 + soct * 8;
  const ushort_t* gAl = gl + (size_t)(m0 + srow) * 2848 + soct * 8;
  const ushort_t* gBh = w2h + (size_t)(n0 + srow) * 2848 + soct * 8;
  const ushort_t* gBl = w2l + (size_t)(n0 + srow) * 2848 + soct * 8;
  ushort_t* lA  = &Ah[srow * 32 + soct * 8];
  ushort_t* lAl = &Al[srow * 32 + soct * 8];
  ushort_t* lB  = &Bh[srow * 32 + soct * 8];
  ushort_t* lBl = &Bl[srow * 32 + soct * 8];
  f32x4 accH[4][2] = {};
  f32x4 accC[4][2] = {};
  for (int k0 = 0; k0 < 2848; k0 += 32) {
    gld16(gAh + k0, lA);
    gld16(gAh + ROW64 + k0, lA + 64 * 32);
    gld16(gAl + k0, lAl);
    gld16(gAl + ROW64 + k0, lAl + 64 * 32);
    gld16(gBh + k0, lB);
    gld16(gBl + k0, lBl);
    __syncthreads();
    f16x8 bhf[2], blf[2];
#pragma unroll
    for (int nt = 0; nt < 2; ++nt) {
      int off = (wn * 32 + nt * 16 + fr) * 32 + quad * 8;
      bhf[nt] = *(const f16x8*)&Bh[off];
      blf[nt] = *(const f16x8*)&Bl[off];
    }
#pragma unroll
    for (int mt = 0; mt < 4; ++mt) {
      int off = (wm * 64 + mt * 16 + fr) * 32 + quad * 8;
      f16x8 ah = *(const f16x8*)&Ah[off];
      f16x8 al = *(const f16x8*)&Al[off];
#pragma unroll
      for (int nt = 0; nt < 2; ++nt) {
        accH[mt][nt] = __builtin_amdgcn_mfma_f32_16x16x32_f16(ah, bhf[nt], accH[mt][nt], 0, 0, 0);
        accC[mt][nt] = __builtin_amdgcn_mfma_f32_16x16x32_f16(ah, blf[nt], accC[mt][nt], 0, 0, 0);
        accC[mt][nt] = __builtin_amdgcn_mfma_f32_16x16x32_f16(al, bhf[nt], accC[mt][nt], 0, 0, 0);
      }
    }
    __syncthreads();
  }
#pragma unroll
  for (int mt = 0; mt < 4; ++mt) {
#pragma unroll
    for (int nt = 0; nt < 2; ++nt) {
      int hh = n0 + wn * 32 + nt * 16 + fr;
      if (hh >= 2809) continue;
      float fb2 = f2b[hh];
#pragma unroll
      for (int r = 0; r < 4; ++r) {
        int m = m0 + wm * 64 + mt * 16 + quad * 4 + r;
        if (m < 192) {
          int bt = m >> 5, ntok = m & 31;
          int b = bt / 3;
          score[(size_t)m * 2809 + hh] = accH[mt][nt][r] + accC[mt][nt][r] * (1.f / 2048.f)
                                       + qs[b * 32 + ntok] * fb2;
        }
      }
    }
  }
}

// ---------------- fused tokenselector ----------------
__global__ void __launch_bounds__(256) sel_fused_kernel(
    const float* __restrict__ xp, const float* __restrict__ dwt, const float* __restrict__ db,
    const float* __restrict__ st, const float* __restrict__ bt,
    const float* __restrict__ pw, const float* __restrict__ pwb, float* __restrict__ sel) {
  __shared__ float row[768];
  __shared__ float part[32][9];
  int p = blockIdx.x;  // 5618
  int b = p / 2809, hw = p - b * 2809;
  int y = hw / 53, x = hw - y * 53;
  for (int c = threadIdx.x; c < 768; c += 256) {
    float acc = db[c];
    float scc = st[c], bcc = bt[c];
#pragma unroll
    for (int dy = 0; dy < 3; ++dy) {
      int yy = y + dy - 1; if (yy < 0 || yy >= 53) continue;
#pragma unroll
      for (int dx = 0; dx < 3; ++dx) {
        int xx = x + dx - 1; if (xx < 0 || xx >= 53) continue;
        float f0v = xp[((size_t)b * 11236 + yy * 53 + xx) * 768 + c] * scc + bcc;
        acc += f0v * dwt[(dy * 3 + dx) * 768 + c];
      }
    }
    row[c] = acc * fminf(fmaxf(acc + 3.f, 0.f), 6.f) * (1.f / 6.f);
  }
  __syncthreads();
  int n = threadIdx.x & 31, lane = threadIdx.x >> 5;
  float acc = 0.f;
  for (int c = lane; c < 768; c += 8) acc += row[c] * pw[n * 768 + c];
  part[n][lane] = acc;
  __syncthreads();
  if (threadIdx.x < 32) {
    float s = pwb[threadIdx.x];
#pragma unroll
    for (int l = 0; l < 8; ++l) s += part[threadIdx.x][l];
    sel[(size_t)(b * 32 + threadIdx.x) * 2809 + hw] = s;
  }
}

// ---------------- token argmax gather (pos computed on the fly) ----------------
__global__ void __launch_bounds__(256) tok_gather_kernel(
    const float* __restrict__ sel, const float* __restrict__ xp,
    const float* __restrict__ st, const float* __restrict__ bt,
    const float* __restrict__ poswt, const float* __restrict__ posb,
    float* __restrict__ out, float* __restrict__ qs) {
  int blk = blockIdx.x;  // 64
  int b = blk >> 5, n = blk & 31;
  const float* srow = sel + (size_t)blk * 2809;
  __shared__ float red[256];
  __shared__ int cnt;
  __shared__ int matches[64];
  float mx = -3.4e38f;
  for (int i = threadIdx.x; i < 2809; i += 256) mx = fmaxf(mx, srow[i]);
  red[threadIdx.x] = mx; __syncthreads();
  for (int off = 128; off > 0; off >>= 1) {
    if (threadIdx.x < off) red[threadIdx.x] = fmaxf(red[threadIdx.x], red[threadIdx.x + off]);
    __syncthreads();
  }
  float m = red[0];
  if (threadIdx.x == 0) cnt = 0;
  __syncthreads();
  for (int i = threadIdx.x; i < 2809; i += 256)
    if (srow[i] == m) { int id = atomicAdd(&cnt, 1); if (id < 64) matches[id] = i; }
  __syncthreads();
  int nm = cnt < 64 ? cnt : 64;
  float accf[3] = {0, 0, 0}, accp[3] = {0, 0, 0};
  float stc[3], btc[3];
#pragma unroll
  for (int i = 0; i < 3; ++i) { int c = threadIdx.x + i * 256; stc[i] = st[c]; btc[i] = bt[c]; }
  for (int j = 0; j < nm; ++j) {
    int hw = matches[j];
    int y = hw / 53, x = hw - y * 53;
#pragma unroll
    for (int i = 0; i < 3; ++i) {
      int c = threadIdx.x + i * 256;
      accf[i] += xp[((size_t)b * 11236 + hw) * 768 + c] * stc[i] + btc[i];
      float pv = posb[c];
      for (int dt = 0; dt < 3; ++dt) {
        int tt = dt - 1; if (tt < 0) continue;  // t=0 frame
        for (int dy = 0; dy < 3; ++dy) {
          int yy = y + dy - 1; if (yy < 0 || yy >= 53) continue;
          for (int dx = 0; dx < 3; ++dx) {
            int xx = x + dx - 1; if (xx < 0 || xx >= 53) continue;
            pv += xp[((size_t)(b * 4 + tt) * 2809 + yy * 53 + xx) * 768 + c]
                * poswt[((dt * 3 + dy) * 3 + dx) * 768 + c];
          }
        }
      }
      accp[i] += pv;
    }
  }
#pragma unroll
  for (int i = 0; i < 3; ++i) {
    int c = threadIdx.x + i * 256;
    out[(size_t)(b * 128 + n) * 768 + c] = accf[i];
    out[196608 + (size_t)(b * 128 + n) * 768 + c] = accp[i];
  }
  float s = accf[0] + accf[1] + accf[2];
  __syncthreads();
  red[threadIdx.x] = s; __syncthreads();
  for (int off = 128; off > 0; off >>= 1) {
    if (threadIdx.x < off) red[threadIdx.x] += red[threadIdx.x + off];
    __syncthreads();
  }
  if (threadIdx.x == 0) qs[blk] = red[0];
}

// ---------------- chain argmax gather (pos on the fly) ----------------
__global__ void __launch_bounds__(256) chain_gather_kernel(
    const float* __restrict__ score, const float* __restrict__ xp,
    const float* __restrict__ sc, const float* __restrict__ bc,
    const float* __restrict__ poswt, const float* __restrict__ posb,
    float* __restrict__ out) {
  int blk = blockIdx.x;  // 192
  int bt = blk >> 5, n = blk & 31;
  int b = bt / 3, t = bt - b * 3;
  const float* srow = score + (size_t)blk * 2809;
  __shared__ float red[256];
  __shared__ int cnt;
  __shared__ int matches[64];
  float mx = -3.4e38f;
  for (int i = threadIdx.x; i < 2809; i += 256) mx = fmaxf(mx, srow[i]);
  red[threadIdx.x] = mx; __syncthreads();
  for (int off = 128; off > 0; off >>= 1) {
    if (threadIdx.x < off) red[threadIdx.x] = fmaxf(red[threadIdx.x], red[threadIdx.x + off]);
    __syncthreads();
  }
  float m = red[0];
  if (threadIdx.x == 0) cnt = 0;
  __syncthreads();
  for (int i = threadIdx.x; i < 2809; i += 256)
    if (srow[i] == m) { int id = atomicAdd(&cnt, 1); if (id < 64) matches[id] = i; }
  __syncthreads();
  int nm = cnt < 64 ? cnt : 64;
  int frame = t + 1;
  float accf[3] = {0, 0, 0}, accp[3] = {0, 0, 0};
  float scc[3], bcc[3];
#pragma unroll
  for (int i = 0; i < 3; ++i) { int c = threadIdx.x + i * 256; scc[i] = sc[c]; bcc[i] = bc[c]; }
  for (int j = 0; j < nm; ++j) {
    int hw = matches[j];
    int y = hw / 53, x = hw - y * 53;
#pragma unroll
    for (int i = 0; i < 3; ++i) {
      int c = threadIdx.x + i * 256;
      size_t idx = ((size_t)(b * 4 + frame) * 2809 + hw) * 768 + c;
      accf[i] += xp[idx] * scc[i] + bcc[i];
      float pv = posb[c];
      for (int dt = 0; dt < 3; ++dt) {
        int tt = frame + dt - 1; if (tt < 0 || tt >= 4) continue;
        for (int dy = 0; dy < 3; ++dy) {
          int yy = y + dy - 1; if (yy < 0 || yy >= 53) continue;
          for (int dx = 0; dx < 3; ++dx) {
            int xx = x + dx - 1; if (xx < 0 || xx >= 53) continue;
            pv += xp[((size_t)(b * 4 + tt) * 2809 + yy * 53 + xx) * 768 + c]
                * poswt[((dt * 3 + dy) * 3 + dx) * 768 + c];
          }
        }
      }
      accp[i] += pv;
    }
  }
#pragma unroll
  for (int i = 0; i < 3; ++i) {
    int c = threadIdx.x + i * 256;
    out[(size_t)((b * 4 + frame) * 32 + n) * 768 + c] = accf[i];
    out[196608 + (size_t)((b * 4 + frame) * 32 + n) * 768 + c] = accp[i];
  }
}

// ---------------- launch ----------------
extern "C" void kernel_launch(void* const* d_in, const int* in_sizes, int n_in,
                              void* d_out, int out_size, void* d_ws, size_t ws_size,
                              hipStream_t stream) {
  const float* x       = (const float*)d_in[0];
  const float* ori     = (const float*)d_in[1];
  const float* bna_g   = (const float*)d_in[2];
  const float* bna_b   = (const float*)d_in[3];
  const float* tconv_w = (const float*)d_in[4];
  const float* tconv_b = (const float*)d_in[5];
  const float* bnp_g   = (const float*)d_in[6];
  const float* bnp_b   = (const float*)d_in[7];
  const float* proj_w  = (const float*)d_in[8];
  const float* proj_b  = (const float*)d_in[9];
  const float* pos_w   = (const float*)d_in[10];
  const float* pos_b   = (const float*)d_in[11];
  const float* bnt_g   = (const float*)d_in[12];
  const float* bnt_b   = (const float*)d_in[13];
  const float* dw_w    = (const float*)d_in[14];
  const float* dw_b    = (const float*)d_in[15];
  const float* pw_w    = (const float*)d_in[16];
  const float* pw_b    = (const float*)d_in[17];
  const float* bnc_g   = (const float*)d_in[18];
  const float* bnc_b   = (const float*)d_in[19];
  const float* fc1_w   = (const float*)d_in[20];
  const float* fc1_b   = (const float*)d_in[21];
  const float* fc2_w   = (const float*)d_in[22];
  const float* fc2_b   = (const float*)d_in[23];
  float* ws  = (float*)d_ws;
  float* out = (float*)d_out;

  if (ws_size < NEED_FLOATS * sizeof(float)) return;  // loud failure (output stays poisoned)

  float* scale_a = ws + OFF_SCALE_A;
  float* bias_a  = ws + OFF_BIAS_A;
  float* pstat   = ws + OFF_PSTAT;
  float* scale_t = ws + OFF_SCALE_T;
  float* bias_t  = ws + OFF_BIAS_T;
  float* scale_c = ws + OFF_SCALE_C;
  float* bias_c  = ws + OFF_BIAS_C;
  float* qsbuf   = ws + OFF_QS;
  float* pb0     = ws + OFF_PB0;
  float* pb1     = ws + OFF_PB1;
  float* poswt   = ws + OFF_POSWT;
  float* dwwt    = ws + OFF_DWWT;
  float* selbuf  = ws + OFF_SEL;
  float* gbuf    = ws + OFF_G;
  float* scorebuf= ws + OFF_SCORE;
  float* xpbuf   = ws + OFF_XP;
  float* sums_c  = scorebuf;          // scratch inside not-yet-written score
  float* sums_t  = scorebuf + 1536;

  ushort_t* vh  = (ushort_t*)(ws + OFF_A + A_VH);
  ushort_t* vl  = (ushort_t*)(ws + OFF_A + A_VL);
  ushort_t* pwh = (ushort_t*)(ws + OFF_A + A_PWH);
  ushort_t* pwl = (ushort_t*)(ws + OFF_A + A_PWL);
  ushort_t* kth = (ushort_t*)(ws + OFF_A + A_KTH);
  ushort_t* ktl = (ushort_t*)(ws + OFF_A + A_KTL);
  ushort_t* w1h = (ushort_t*)(ws + OFF_W1H);
  ushort_t* w1l = (ushort_t*)(ws + OFF_W1L);
  ushort_t* w2h = (ushort_t*)(ws + OFF_W2H);
  ushort_t* w2l = (ushort_t*)(ws + OFF_W2L);
  ushort_t* gh  = (ushort_t*)(ws + OFF_GH);
  ushort_t* gl  = (ushort_t*)(ws + OFF_GL);

  hipMemsetAsync(pstat, 0, 16 * sizeof(float), stream);
  hipMemsetAsync(sums_c, 0, 3072 * sizeof(float), stream);
  hipMemsetAsync(gbuf, 0, 545472 * sizeof(float), stream);

  bn_stats_x_kernel<<<320, 256, 0, stream>>>(x, bna_g, bna_b, scale_a, bias_a);
  tconv_gemm_kernel<<<dim3(25, 24), 256, 0, stream>>>(x, tconv_w, tconv_b, ori, scale_a, bias_a, vh, vl);
  bnp_partial_kernel<<<192, 256, 0, stream>>>(vh, vl, pstat);
  bnp_final_kernel<<<1, 64, 0, stream>>>(pstat, bnp_g, bnp_b);
  pwfold_kernel<<<768, 256, 0, stream>>>(proj_w, proj_b, pstat, pwh, pwl, pb0, pb1);
  mfma_proj_kernel<<<dim3(176, 12), 256, 0, stream>>>(vh, vl, pwh, pwl, pb0, pb1, xpbuf);
  bn_sums_cl_kernel<<<44, 256, 0, stream>>>(xpbuf, sums_t, 1, 5618);
  bn_sums_cl_kernel<<<176, 256, 0, stream>>>(xpbuf, sums_c, 0, 22472);
  bn_finalize_kernel<<<3, 256, 0, stream>>>(sums_t, bnt_g, bnt_b, scale_t, bias_t, 5618.f);
  bn_finalize_kernel<<<3, 256, 0, stream>>>(sums_c, bnc_g, bnc_b, scale_c, bias_c, 22472.f);
  wtrans_kernel<<<81, 256, 0, stream>>>(pos_w, dw_w, poswt, dwwt);
  sel_fused_kernel<<<5618, 256, 0, stream>>>(xpbuf, dwwt, dw_b, scale_t, bias_t, pw_w, pw_b, selbuf);
  tok_gather_kernel<<<64, 256, 0, stream>>>(selbuf, xpbuf, scale_t, bias_t, poswt, pos_b, out, qsbuf);
  ktrans_kernel<<<dim3(72, 45), 256, 0, stream>>>(xpbuf, out, scale_c, bias_c, kth, ktl);
  w1conv_kernel<<<2944, 256, 0, stream>>>(fc1_w, w1h, w1l);
  w2conv_kernel<<<2816, 256, 0, stream>>>(fc2_w, w2h, w2l);
  mfma_fc1_kernel<<<dim3(36, 46), 256, 0, stream>>>(kth, ktl, w1h, w1l, fc1_b, out, gbuf);
  gconv_kernel<<<256, 256, 0, stream>>>(gbuf, gh, gl);
  mfma_score_kernel<<<dim3(2, 44), 256, 0, stream>>>(gh, gl, w2h, w2l, fc2_b, qsbuf, scorebuf);
  chain_gather_kernel<<<192, 256, 0, stream>>>(scorebuf, xpbuf, scale_c, bias_c, poswt, pos_b, out);
}